// Round 1
// baseline (735.256 us; speedup 1.0000x reference)
//
#include <hip/hip_runtime.h>
#include <hip/hip_bf16.h>

#define NUM_CLASSES 100000
#define NUM_SAMPLED 5000
#define BATCH 4096
#define DIM 1024
#define NPAD 5120   // 5000 padded to 40 tiles of 128
#define NLINES 6250 // 100000 classes / 16 per 64B line
#define SLACK 32    // max bucket entries per line (Poisson lambda~1.46, P(>32)~1e-30)

typedef float floatx4 __attribute__((ext_vector_type(4)));
typedef short bf16x8 __attribute__((ext_vector_type(8)));

// ---------------------------------------------------------------- helpers
__device__ __forceinline__ float log_expected_count(int c) {
    // p = log((c+2)/(c+1)) / log(NUM_CLASSES+1)
    float p = log1pf(1.0f / (float)(c + 1)) / logf((float)NUM_CLASSES + 1.0f);
    float t = (float)NUM_SAMPLED * log1pf(-p);
    return logf(-expm1f(t));
}

__device__ __forceinline__ void async_ld16(const void* g, void* l) {
    __builtin_amdgcn_global_load_lds(
        (const __attribute__((address_space(1))) unsigned int*)g,
        (__attribute__((address_space(3))) unsigned int*)l,
        16, 0, 0);
}

// ---------------------------------------------------------------- setup: zero cnt, rowsum, BT padding rows
__global__ __launch_bounds__(256) void setup_kernel(int* __restrict__ cnt,
                                                    float* __restrict__ rowsum,
                                                    uint4* __restrict__ btpad) {
    int i = blockIdx.x * 256 + threadIdx.x;   // 16384 threads
    if (i < NLINES) cnt[i] = 0;
    if (i < BATCH) rowsum[i] = 0.0f;
    if (i < (NPAD - NUM_SAMPLED) * DIM * 2 / 16) {  // 15360 uint4 = 120 rows of bf16
        uint4 z; z.x = z.y = z.z = z.w = 0u;
        btpad[i] = z;
    }
}

// ---------------------------------------------------------------- x -> bf16
__global__ __launch_bounds__(256) void convert_x_kernel(const float* __restrict__ x,
                                                        __hip_bfloat16* __restrict__ A) {
    int i = (blockIdx.x * 256 + threadIdx.x) * 4;
    float4 v = *reinterpret_cast<const float4*>(x + i);
    union { ushort4 u; __hip_bfloat16 h[4]; } o;
    o.h[0] = __float2bfloat16(v.x);
    o.h[1] = __float2bfloat16(v.y);
    o.h[2] = __float2bfloat16(v.z);
    o.h[3] = __float2bfloat16(v.w);
    *reinterpret_cast<ushort4*>(A + i) = o.u;
}

// ---------------------------------------------------------------- bucket fill: group sampled+label classes by 64B line of w
// entry = slot(4b)<<28 | isLabel(1b)<<27 | idx(14b)
// also computes shift[n] = b[c] - logE(c) (pad -1e30) and tlshift[m] = b[lbl] - logE(lbl)
__global__ __launch_bounds__(256) void bucket_kernel(const int* __restrict__ sampled,
                                                     const int* __restrict__ labels,
                                                     const float* __restrict__ b,
                                                     int* __restrict__ cnt,
                                                     unsigned* __restrict__ entries,
                                                     float* __restrict__ shift,
                                                     float* __restrict__ tlshift) {
    int t = blockIdx.x * 256 + threadIdx.x;   // 9216 threads
    if (t < NUM_SAMPLED) {
        int c = sampled[t];
        int pos = atomicAdd(&cnt[c >> 4], 1);
        if (pos < SLACK)
            entries[(c >> 4) * SLACK + pos] = ((unsigned)(c & 15) << 28) | (unsigned)t;
        shift[t] = b[c] - log_expected_count(c);
    } else if (t < NPAD) {
        shift[t] = -1e30f;
    } else if (t < NPAD + BATCH) {
        int m = t - NPAD;
        int c = labels[m];
        int pos = atomicAdd(&cnt[c >> 4], 1);
        if (pos < SLACK)
            entries[(c >> 4) * SLACK + pos] = ((unsigned)(c & 15) << 28) | (1u << 27) | (unsigned)m;
        tlshift[m] = b[c] - log_expected_count(c);
    }
}

// ---------------------------------------------------------------- streaming extractor: one coalesced pass over active w lines
// thread = (d, line). Consecutive lanes hit consecutive 64B lines -> dense HBM reads.
// Writes BT[n][d] (bf16, GEMM operand) and WT[m][d] (fp32, exact true-logit path).
__global__ __launch_bounds__(256) void extract_kernel(const float* __restrict__ w,
                                                      const int* __restrict__ cnt,
                                                      const unsigned* __restrict__ entries,
                                                      __hip_bfloat16* __restrict__ BT,
                                                      float* __restrict__ WT) {
    int line = blockIdx.x * 256 + threadIdx.x;   // 25 blocks x -> 6400 >= 6250
    int d = blockIdx.y;                          // 1024
    if (line >= NLINES) return;
    int c = cnt[line];
    if (c == 0) return;
    if (c > SLACK) c = SLACK;
    const float* src = w + (size_t)d * NUM_CLASSES + line * 16;
    for (int e = 0; e < c; e++) {
        unsigned E = entries[line * SLACK + e];
        float v = src[E >> 28];                  // 4B from the just-fetched line (L1-hot)
        unsigned idx = E & 0x3FFFu;
        if (E & (1u << 27)) WT[(size_t)idx * DIM + d] = v;
        else                BT[(size_t)idx * DIM + d] = __float2bfloat16(v);
    }
}

// ---------------------------------------------------------------- GEMM 4096x5120x1024 bf16 + fused exp-rowsum epilogue
// A: [M][K] bf16 row-major.  BT: [N][K] bf16 row-major.  acc = A·B.
// Epilogue: rowsum[m] += sum_n exp(acc[m][n] + shift[n])
#define BM 128
#define BN 128
#define BK 64

__global__ __launch_bounds__(256) void gemm_kernel(const __hip_bfloat16* __restrict__ A,
                                                   const __hip_bfloat16* __restrict__ BT,
                                                   const float* __restrict__ shift,
                                                   float* __restrict__ rowsum) {
    __shared__ __hip_bfloat16 As[BM * BK];   // 16 KB
    __shared__ __hip_bfloat16 Bs[BN * BK];   // 16 KB

    const int tid  = threadIdx.x;
    const int m0   = blockIdx.x * BM;   // 32 m-tiles
    const int n0   = blockIdx.y * BN;   // 40 n-tiles
    const int lane = tid & 63;
    const int wv   = tid >> 6;          // wave 0..3
    const int wm   = (wv >> 1) * 64;    // 2x2 wave layout of 64x64 quadrants
    const int wn   = (wv & 1) * 64;
    const int col  = lane & 15;
    const int quad = lane >> 4;

    floatx4 acc[4][4] = {};

    // staging: thread stages 16B at LDS byte offset tid*16 + r*4096, r=0..3
    // (wave-uniform base + lane*16 as required by global_load_lds)
    const __hip_bfloat16* gA[4];
    const __hip_bfloat16* gB[4];
    int ldsOff[4];
    #pragma unroll
    for (int r = 0; r < 4; r++) {
        int eo  = tid * 8 + r * 2048;     // element offset in [128][64] tile
        int row = eo >> 6;
        int cl  = eo & 63;
        gA[r] = A  + (size_t)(m0 + row) * DIM + cl;
        gB[r] = BT + (size_t)(n0 + row) * DIM + cl;
        ldsOff[r] = eo;
    }

    for (int kt = 0; kt < DIM; kt += BK) {
        #pragma unroll
        for (int r = 0; r < 4; r++)
            async_ld16(gA[r] + kt, &As[ldsOff[r]]);
        #pragma unroll
        for (int r = 0; r < 4; r++)
            async_ld16(gB[r] + kt, &Bs[ldsOff[r]]);
        __syncthreads();   // drains vmcnt before LDS reads

        #pragma unroll
        for (int ks = 0; ks < 2; ks++) {
            const int kc = ks * 32 + quad * 8;
            bf16x8 af[4], bfr[4];
            #pragma unroll
            for (int i = 0; i < 4; i++) {
                af[i]  = *reinterpret_cast<const bf16x8*>(&As[(wm + i * 16 + col) * BK + kc]);
                bfr[i] = *reinterpret_cast<const bf16x8*>(&Bs[(wn + i * 16 + col) * BK + kc]);
            }
            #pragma unroll
            for (int i = 0; i < 4; i++)
                #pragma unroll
                for (int j = 0; j < 4; j++)
                    acc[i][j] = __builtin_amdgcn_mfma_f32_16x16x32_bf16(af[i], bfr[j], acc[i][j], 0, 0, 0);
        }
        __syncthreads();
    }

    // ---- fused epilogue: per-row sum of exp(logit + shift[n])
    // C/D layout: col = lane&15 (n), row = quad*4 + reg (m)
    float sh[4];
    #pragma unroll
    for (int j = 0; j < 4; j++)
        sh[j] = shift[n0 + wn + j * 16 + col];

    #pragma unroll
    for (int i = 0; i < 4; i++) {
        #pragma unroll
        for (int r = 0; r < 4; r++) {
            float s = 0.0f;
            #pragma unroll
            for (int j = 0; j < 4; j++)
                s += __expf(acc[i][j][r] + sh[j]);
            // reduce across the 16 n-lanes (lane bits 0..3) — rows identical there
            s += __shfl_xor(s, 1);
            s += __shfl_xor(s, 2);
            s += __shfl_xor(s, 4);
            s += __shfl_xor(s, 8);
            if (col == 0) {
                int mrow = m0 + wm + i * 16 + quad * 4 + r;
                atomicAdd(&rowsum[mrow], s);   // 4096 distinct addresses, ~20 contenders each — fine
            }
        }
    }
}

// ---------------------------------------------------------------- per-row true logit from gathered fp32 WT (coalesced)
__global__ __launch_bounds__(256) void rowloss_kernel(const float* __restrict__ x,
                                                      const float* __restrict__ WT,
                                                      const float* __restrict__ tlshift,
                                                      const float* __restrict__ rowsum,
                                                      float* __restrict__ rowloss) {
    int m = blockIdx.x * 4 + (threadIdx.x >> 6);   // one wave per row, 4 rows/block
    int lane = threadIdx.x & 63;
    const float4* xr = reinterpret_cast<const float4*>(x + (size_t)m * DIM);
    const float4* wr = reinterpret_cast<const float4*>(WT + (size_t)m * DIM);
    float p = 0.0f;
    #pragma unroll
    for (int j = 0; j < 4; j++) {
        float4 a = xr[lane + 64 * j];
        float4 b = wr[lane + 64 * j];
        p += a.x * b.x + a.y * b.y + a.z * b.z + a.w * b.w;
    }
    #pragma unroll
    for (int off = 32; off > 0; off >>= 1)
        p += __shfl_xor(p, off);
    if (lane == 0) {
        float tl = p + tlshift[m];
        float total = rowsum[m] + __expf(tl);
        rowloss[m] = logf(total) - tl;
    }
}

// ---------------------------------------------------------------- final mean over 4096 row losses (1 block)
__global__ __launch_bounds__(256) void reduce_kernel(const float* __restrict__ rowloss,
                                                     float* __restrict__ out) {
    __shared__ float red[4];
    const int t = threadIdx.x;
    float s = 0.0f;
    #pragma unroll
    for (int i = t; i < BATCH; i += 256)
        s += rowloss[i];
    #pragma unroll
    for (int off = 32; off > 0; off >>= 1)
        s += __shfl_xor(s, off);
    if ((t & 63) == 0) red[t >> 6] = s;
    __syncthreads();
    if (t == 0)
        out[0] = (red[0] + red[1] + red[2] + red[3]) * (1.0f / (float)BATCH);
}

// ---------------------------------------------------------------- launch
extern "C" void kernel_launch(void* const* d_in, const int* in_sizes, int n_in,
                              void* d_out, int out_size, void* d_ws, size_t ws_size,
                              hipStream_t stream) {
    const float* x       = (const float*)d_in[0];
    const float* w       = (const float*)d_in[1];
    const float* b       = (const float*)d_in[2];
    const int*   labels  = (const int*)d_in[3];
    const int*   sampled = (const int*)d_in[4];
    float* out = (float*)d_out;

    char* ws = (char*)d_ws;
    __hip_bfloat16* A  = (__hip_bfloat16*)(ws);                             // 8 MB
    __hip_bfloat16* BT = (__hip_bfloat16*)(ws + (size_t)8  * 1024 * 1024);  // 10 MB
    float* WT      = (float*)(ws + (size_t)18 * 1024 * 1024);               // 16 MB
    float* shift   = (float*)(ws + (size_t)34 * 1024 * 1024);               // 20 KB
    float* tlshift = (float*)(ws + (size_t)34 * 1024 * 1024 + 64  * 1024);  // 16 KB
    float* rowsum  = (float*)(ws + (size_t)34 * 1024 * 1024 + 128 * 1024);  // 16 KB
    float* rowloss = (float*)(ws + (size_t)34 * 1024 * 1024 + 192 * 1024);  // 16 KB
    int* cnt       = (int*)  (ws + (size_t)34 * 1024 * 1024 + 256 * 1024);  // 25 KB
    unsigned* ent  = (unsigned*)(ws + (size_t)34 * 1024 * 1024 + 320 * 1024); // 800 KB

    hipLaunchKernelGGL(setup_kernel, dim3(64), dim3(256), 0, stream,
                       cnt, rowsum, (uint4*)(BT + (size_t)NUM_SAMPLED * DIM));
    hipLaunchKernelGGL(convert_x_kernel, dim3((BATCH * DIM / 4) / 256), dim3(256), 0, stream, x, A);
    hipLaunchKernelGGL(bucket_kernel, dim3((NPAD + BATCH) / 256), dim3(256), 0, stream,
                       sampled, labels, b, cnt, ent, shift, tlshift);
    hipLaunchKernelGGL(extract_kernel, dim3((NLINES + 255) / 256, DIM), dim3(256), 0, stream,
                       w, cnt, ent, BT, WT);
    hipLaunchKernelGGL(gemm_kernel, dim3(BATCH / BM, NPAD / BN), dim3(256), 0, stream,
                       A, BT, shift, rowsum);
    hipLaunchKernelGGL(rowloss_kernel, dim3(BATCH / 4), dim3(256), 0, stream,
                       x, WT, tlshift, rowsum, rowloss);
    hipLaunchKernelGGL(reduce_kernel, dim3(1), dim3(256), 0, stream, rowloss, out);
}

// Round 3
// 659.007 us; speedup vs baseline: 1.1157x; 1.1157x over previous
//
#include <hip/hip_runtime.h>
#include <hip/hip_bf16.h>

#define NUM_CLASSES 100000
#define NUM_SAMPLED 5000
#define BATCH 4096
#define DIM 1024
#define NPAD 5120   // 5000 padded to 40 tiles of 128
#define NLINES 6250 // 100000 classes / 16 per 64B line
#define SLACK 32    // max bucket entries per line (Poisson lambda~1.46, P(>32)~1e-30)

typedef float floatx4 __attribute__((ext_vector_type(4)));
typedef short bf16x8 __attribute__((ext_vector_type(8)));

// ---------------------------------------------------------------- helpers
__device__ __forceinline__ float log_expected_count(int c) {
    // p = log((c+2)/(c+1)) / log(NUM_CLASSES+1)
    float p = log1pf(1.0f / (float)(c + 1)) / logf((float)NUM_CLASSES + 1.0f);
    float t = (float)NUM_SAMPLED * log1pf(-p);
    return logf(-expm1f(t));
}

__device__ __forceinline__ void async_ld16(const void* g, void* l) {
    __builtin_amdgcn_global_load_lds(
        (const __attribute__((address_space(1))) unsigned int*)g,
        (__attribute__((address_space(3))) unsigned int*)l,
        16, 0, 0);
}

// ---------------------------------------------------------------- setup: zero cnt, rowsum, BT padding rows
__global__ __launch_bounds__(256) void setup_kernel(int* __restrict__ cnt,
                                                    float* __restrict__ rowsum,
                                                    uint4* __restrict__ btpad) {
    int i = blockIdx.x * 256 + threadIdx.x;   // 16384 threads
    if (i < NLINES) cnt[i] = 0;
    if (i < BATCH) rowsum[i] = 0.0f;
    if (i < (NPAD - NUM_SAMPLED) * DIM * 2 / 16) {  // 15360 uint4 = 120 rows of bf16
        uint4 z; z.x = z.y = z.z = z.w = 0u;
        btpad[i] = z;
    }
}

// ---------------------------------------------------------------- x -> bf16
__global__ __launch_bounds__(256) void convert_x_kernel(const float* __restrict__ x,
                                                        __hip_bfloat16* __restrict__ A) {
    int i = (blockIdx.x * 256 + threadIdx.x) * 4;
    float4 v = *reinterpret_cast<const float4*>(x + i);
    union { ushort4 u; __hip_bfloat16 h[4]; } o;
    o.h[0] = __float2bfloat16(v.x);
    o.h[1] = __float2bfloat16(v.y);
    o.h[2] = __float2bfloat16(v.z);
    o.h[3] = __float2bfloat16(v.w);
    *reinterpret_cast<ushort4*>(A + i) = o.u;
}

// ---------------------------------------------------------------- bucket fill: group sampled+label classes by 64B line of w
// entry = slot(4b)<<28 | isLabel(1b)<<27 | idx(14b)
// also computes shift[n] = b[c] - logE(c) (pad -1e30) and tlshift[m] = b[lbl] - logE(lbl)
__global__ __launch_bounds__(256) void bucket_kernel(const int* __restrict__ sampled,
                                                     const int* __restrict__ labels,
                                                     const float* __restrict__ b,
                                                     int* __restrict__ cnt,
                                                     unsigned* __restrict__ entries,
                                                     float* __restrict__ shift,
                                                     float* __restrict__ tlshift) {
    int t = blockIdx.x * 256 + threadIdx.x;   // 9216 threads
    if (t < NUM_SAMPLED) {
        int c = sampled[t];
        int pos = atomicAdd(&cnt[c >> 4], 1);
        if (pos < SLACK)
            entries[(c >> 4) * SLACK + pos] = ((unsigned)(c & 15) << 28) | (unsigned)t;
        shift[t] = b[c] - log_expected_count(c);
    } else if (t < NPAD) {
        shift[t] = -1e30f;
    } else if (t < NPAD + BATCH) {
        int m = t - NPAD;
        int c = labels[m];
        int pos = atomicAdd(&cnt[c >> 4], 1);
        if (pos < SLACK)
            entries[(c >> 4) * SLACK + pos] = ((unsigned)(c & 15) << 28) | (1u << 27) | (unsigned)m;
        tlshift[m] = b[c] - log_expected_count(c);
    }
}

// ---------------------------------------------------------------- transpose-extract:
// block = 64 w-lines (1024 classes) x 32 d-values. Read pass: coalesced-by-cache-line
// gather of active entries into LDS tile val[32 d][<=128 entries] (fp32).
// Write pass: per entry, 32 contiguous d-values -> BT (bf16, 64B/row-seg) or WT (fp32, 128B).
// Kills the round-1 scatter-write RMW (~590 MB -> 26 MB of writes).
#define LPB 64    // lines per block
#define DPB 32    // d per block
#define ECHUNK 128
#define LISTCAP 512

__global__ __launch_bounds__(256) void extract_kernel(const float* __restrict__ w,
                                                      const int* __restrict__ cnt,
                                                      const unsigned* __restrict__ entries,
                                                      __hip_bfloat16* __restrict__ BT,
                                                      float* __restrict__ WT) {
    __shared__ float val[DPB][ECHUNK];     // 16 KB
    __shared__ unsigned list[LISTCAP];     // 2 KB
    __shared__ int ecount;

    const int tid = threadIdx.x;
    const int L0  = blockIdx.x * LPB;      // line base (98 blocks cover 6250)
    const int d0  = blockIdx.y * DPB;      // 32 d-blocks
    const int C0  = L0 * 16;               // class base

    if (tid == 0) ecount = 0;
    __syncthreads();

    // ---- compact this block's entries into an LDS list
    // packed: c_local(10b)<<16 | isLabel<<15 | idx(15b)
    if (tid < LPB) {
        int line = L0 + tid;
        if (line < NLINES) {
            int c = cnt[line];
            if (c > SLACK) c = SLACK;
            for (int e = 0; e < c; e++) {
                unsigned E = entries[line * SLACK + e];
                int pos = atomicAdd(&ecount, 1);
                if (pos < LISTCAP)
                    list[pos] = ((unsigned)(tid * 16 + (E >> 28)) << 16)
                              | (((E >> 27) & 1u) << 15)
                              | (E & 0x3FFFu);
            }
        }
    }
    __syncthreads();
    int E_blk = ecount;
    if (E_blk > LISTCAP) E_blk = LISTCAP;
    if (E_blk == 0) return;

    for (int base = 0; base < E_blk; base += ECHUNK) {
        int Ec = E_blk - base;
        if (Ec > ECHUNK) Ec = ECHUNK;

        // ---- read pass: lanes sweep entries (e fastest) -> scattered 4B reads that
        // aggregate to whole 64B lines within this block's 4KB class window
        for (int i = tid; i < DPB * ECHUNK; i += 256) {
            int e  = i & (ECHUNK - 1);
            int dj = i >> 7;
            if (e < Ec) {
                unsigned L = list[base + e];
                int cl = L >> 16;
                val[dj][e] = w[(size_t)(d0 + dj) * NUM_CLASSES + C0 + cl];
            }
        }
        __syncthreads();

        // ---- write pass: thread = (entry e, 8-d chunk ch). Contiguous stores.
        for (int i = tid; i < 4 * ECHUNK; i += 256) {
            int e  = i & (ECHUNK - 1);
            int ch = i >> 7;
            if (e < Ec) {
                unsigned L = list[base + e];
                unsigned idx = L & 0x7FFFu;
                int dj = ch * 8;
                if (L & (1u << 15)) {
                    // label -> fp32 WT row
                    float4 a = { val[dj+0][e], val[dj+1][e], val[dj+2][e], val[dj+3][e] };
                    float4 c = { val[dj+4][e], val[dj+5][e], val[dj+6][e], val[dj+7][e] };
                    float4* dst = reinterpret_cast<float4*>(WT + (size_t)idx * DIM + d0 + dj);
                    dst[0] = a; dst[1] = c;
                } else {
                    // sampled -> bf16 BT row
                    union { uint4 u; __hip_bfloat16 h[8]; } o;
                    #pragma unroll
                    for (int j = 0; j < 8; j++)
                        o.h[j] = __float2bfloat16(val[dj + j][e]);
                    *reinterpret_cast<uint4*>(BT + (size_t)idx * DIM + d0 + dj) = o.u;
                }
            }
        }
        __syncthreads();
    }
}

// ---------------------------------------------------------------- GEMM 4096x5120x1024 bf16 + fused exp-rowsum epilogue
// A: [M][K] bf16 row-major.  BT: [N][K] bf16 row-major.  acc = A·B.
// Epilogue: rowsum[m] += sum_n exp(acc[m][n] + shift[n])
#define BM 128
#define BN 128
#define BK 64

__global__ __launch_bounds__(256) void gemm_kernel(const __hip_bfloat16* __restrict__ A,
                                                   const __hip_bfloat16* __restrict__ BT,
                                                   const float* __restrict__ shift,
                                                   float* __restrict__ rowsum) {
    __shared__ __hip_bfloat16 As[BM * BK];   // 16 KB
    __shared__ __hip_bfloat16 Bs[BN * BK];   // 16 KB

    const int tid  = threadIdx.x;
    const int m0   = blockIdx.x * BM;   // 32 m-tiles
    const int n0   = blockIdx.y * BN;   // 40 n-tiles
    const int lane = tid & 63;
    const int wv   = tid >> 6;          // wave 0..3
    const int wm   = (wv >> 1) * 64;    // 2x2 wave layout of 64x64 quadrants
    const int wn   = (wv & 1) * 64;
    const int col  = lane & 15;
    const int quad = lane >> 4;

    floatx4 acc[4][4] = {};

    // staging: thread stages 16B at LDS byte offset tid*16 + r*4096, r=0..3
    // (wave-uniform base + lane*16 as required by global_load_lds)
    const __hip_bfloat16* gA[4];
    const __hip_bfloat16* gB[4];
    int ldsOff[4];
    #pragma unroll
    for (int r = 0; r < 4; r++) {
        int eo  = tid * 8 + r * 2048;     // element offset in [128][64] tile
        int row = eo >> 6;
        int cl  = eo & 63;
        gA[r] = A  + (size_t)(m0 + row) * DIM + cl;
        gB[r] = BT + (size_t)(n0 + row) * DIM + cl;
        ldsOff[r] = eo;
    }

    for (int kt = 0; kt < DIM; kt += BK) {
        #pragma unroll
        for (int r = 0; r < 4; r++)
            async_ld16(gA[r] + kt, &As[ldsOff[r]]);
        #pragma unroll
        for (int r = 0; r < 4; r++)
            async_ld16(gB[r] + kt, &Bs[ldsOff[r]]);
        __syncthreads();   // drains vmcnt before LDS reads

        #pragma unroll
        for (int ks = 0; ks < 2; ks++) {
            const int kc = ks * 32 + quad * 8;
            bf16x8 af[4], bfr[4];
            #pragma unroll
            for (int i = 0; i < 4; i++) {
                af[i]  = *reinterpret_cast<const bf16x8*>(&As[(wm + i * 16 + col) * BK + kc]);
                bfr[i] = *reinterpret_cast<const bf16x8*>(&Bs[(wn + i * 16 + col) * BK + kc]);
            }
            #pragma unroll
            for (int i = 0; i < 4; i++)
                #pragma unroll
                for (int j = 0; j < 4; j++)
                    acc[i][j] = __builtin_amdgcn_mfma_f32_16x16x32_bf16(af[i], bfr[j], acc[i][j], 0, 0, 0);
        }
        __syncthreads();
    }

    // ---- fused epilogue: per-row sum of exp(logit + shift[n])
    // C/D layout: col = lane&15 (n), row = quad*4 + reg (m)
    float sh[4];
    #pragma unroll
    for (int j = 0; j < 4; j++)
        sh[j] = shift[n0 + wn + j * 16 + col];

    #pragma unroll
    for (int i = 0; i < 4; i++) {
        #pragma unroll
        for (int r = 0; r < 4; r++) {
            float s = 0.0f;
            #pragma unroll
            for (int j = 0; j < 4; j++)
                s += __expf(acc[i][j][r] + sh[j]);
            // reduce across the 16 n-lanes (lane bits 0..3) — rows identical there
            s += __shfl_xor(s, 1);
            s += __shfl_xor(s, 2);
            s += __shfl_xor(s, 4);
            s += __shfl_xor(s, 8);
            if (col == 0) {
                int mrow = m0 + wm + i * 16 + quad * 4 + r;
                atomicAdd(&rowsum[mrow], s);   // 4096 distinct addresses, ~20 contenders each — fine
            }
        }
    }
}

// ---------------------------------------------------------------- per-row true logit from gathered fp32 WT (coalesced)
__global__ __launch_bounds__(256) void rowloss_kernel(const float* __restrict__ x,
                                                      const float* __restrict__ WT,
                                                      const float* __restrict__ tlshift,
                                                      const float* __restrict__ rowsum,
                                                      float* __restrict__ rowloss) {
    int m = blockIdx.x * 4 + (threadIdx.x >> 6);   // one wave per row, 4 rows/block
    int lane = threadIdx.x & 63;
    const float4* xr = reinterpret_cast<const float4*>(x + (size_t)m * DIM);
    const float4* wr = reinterpret_cast<const float4*>(WT + (size_t)m * DIM);
    float p = 0.0f;
    #pragma unroll
    for (int j = 0; j < 4; j++) {
        float4 a = xr[lane + 64 * j];
        float4 b = wr[lane + 64 * j];
        p += a.x * b.x + a.y * b.y + a.z * b.z + a.w * b.w;
    }
    #pragma unroll
    for (int off = 32; off > 0; off >>= 1)
        p += __shfl_xor(p, off);
    if (lane == 0) {
        float tl = p + tlshift[m];
        float total = rowsum[m] + __expf(tl);
        rowloss[m] = logf(total) - tl;
    }
}

// ---------------------------------------------------------------- final mean over 4096 row losses (1 block)
__global__ __launch_bounds__(256) void reduce_kernel(const float* __restrict__ rowloss,
                                                     float* __restrict__ out) {
    __shared__ float red[4];
    const int t = threadIdx.x;
    float s = 0.0f;
    #pragma unroll
    for (int i = t; i < BATCH; i += 256)
        s += rowloss[i];
    #pragma unroll
    for (int off = 32; off > 0; off >>= 1)
        s += __shfl_xor(s, off);
    if ((t & 63) == 0) red[t >> 6] = s;
    __syncthreads();
    if (t == 0)
        out[0] = (red[0] + red[1] + red[2] + red[3]) * (1.0f / (float)BATCH);
}

// ---------------------------------------------------------------- launch
extern "C" void kernel_launch(void* const* d_in, const int* in_sizes, int n_in,
                              void* d_out, int out_size, void* d_ws, size_t ws_size,
                              hipStream_t stream) {
    const float* x       = (const float*)d_in[0];
    const float* w       = (const float*)d_in[1];
    const float* b       = (const float*)d_in[2];
    const int*   labels  = (const int*)d_in[3];
    const int*   sampled = (const int*)d_in[4];
    float* out = (float*)d_out;

    char* ws = (char*)d_ws;
    __hip_bfloat16* A  = (__hip_bfloat16*)(ws);                             // 8 MB
    __hip_bfloat16* BT = (__hip_bfloat16*)(ws + (size_t)8  * 1024 * 1024);  // 10 MB
    float* WT      = (float*)(ws + (size_t)18 * 1024 * 1024);               // 16 MB
    float* shift   = (float*)(ws + (size_t)34 * 1024 * 1024);               // 20 KB
    float* tlshift = (float*)(ws + (size_t)34 * 1024 * 1024 + 64  * 1024);  // 16 KB
    float* rowsum  = (float*)(ws + (size_t)34 * 1024 * 1024 + 128 * 1024);  // 16 KB
    float* rowloss = (float*)(ws + (size_t)34 * 1024 * 1024 + 192 * 1024);  // 16 KB
    int* cnt       = (int*)  (ws + (size_t)34 * 1024 * 1024 + 256 * 1024);  // 25 KB
    unsigned* ent  = (unsigned*)(ws + (size_t)34 * 1024 * 1024 + 320 * 1024); // 800 KB

    hipLaunchKernelGGL(setup_kernel, dim3(64), dim3(256), 0, stream,
                       cnt, rowsum, (uint4*)(BT + (size_t)NUM_SAMPLED * DIM));
    hipLaunchKernelGGL(convert_x_kernel, dim3((BATCH * DIM / 4) / 256), dim3(256), 0, stream, x, A);
    hipLaunchKernelGGL(bucket_kernel, dim3((NPAD + BATCH) / 256), dim3(256), 0, stream,
                       sampled, labels, b, cnt, ent, shift, tlshift);
    hipLaunchKernelGGL(extract_kernel, dim3((NLINES + LPB - 1) / LPB, DIM / DPB), dim3(256), 0, stream,
                       w, cnt, ent, BT, WT);
    hipLaunchKernelGGL(gemm_kernel, dim3(BATCH / BM, NPAD / BN), dim3(256), 0, stream,
                       A, BT, shift, rowsum);
    hipLaunchKernelGGL(rowloss_kernel, dim3(BATCH / 4), dim3(256), 0, stream,
                       x, WT, tlshift, rowsum, rowloss);
    hipLaunchKernelGGL(reduce_kernel, dim3(1), dim3(256), 0, stream, rowloss, out);
}